// Round 1
// baseline (1394.626 us; speedup 1.0000x reference)
//
#include <hip/hip_runtime.h>
#include <cmath>
#include <cstring>
#include <mutex>
#include <algorithm>

#ifndef M_PI
#define M_PI 3.14159265358979323846
#endif

// ---------------- problem constants ----------------
// B_IN=32, B_OUT=16, BATCH=32, F_IN=64, F_OUT=32, GRID=24
// lm index: l*l + (m+l), l=0..15, m=-l..l  -> 256
// pack index for (l,m,n): off_l + (m+l)*(2l+1)+(n+l), off_l = l(4l^2-1)/3 -> 5456
#define NLM   256
#define NPACK 5456
#define NMN   961   // 31*31 (m,n) pairs

struct Tables {
  float Wt[NLM * 64];     // [lm][beta_in b] : w[b]*d^l_{m,0}(beta_b), f32 (matches ref cast)
  float Yre[24 * NLM];    // [g][lm]
  float Yim[24 * NLM];
  float Dp[32 * NPACK];   // [b][mn-packed l-runs] : (2l+1)*d^l_{m,n}(beta_out_b)
  float c64[64], s64[64]; // e^{2pi t/64} cos/sin
  float c32[32], s32[32];
  int   mn_off[NMN];      // run offset per (m,n), run len = 16-max(|m|,|n|)
};

__constant__ int d_off[17] = {0,1,10,35,84,165,286,455,680,969,1330,1771,
                              2300,2925,3654,4495,5456};

// ---------------- host-side table construction (f64 -> f32, matches reference) ----
static void h_wigner(int l, double beta, double* d) { // (2l+1)^2, row i=mp+l, col j=mm+l
  double cb = std::cos(beta * 0.5), sb = std::sin(beta * 0.5);
  int L = 2 * l + 1;
  for (int i = 0; i < L; i++) {
    int mp = i - l;
    for (int j = 0; j < L; j++) {
      int mm = j - l;
      double pref = 0.5 * (std::lgamma(l + mp + 1.0) + std::lgamma(l - mp + 1.0) +
                           std::lgamma(l + mm + 1.0) + std::lgamma(l - mm + 1.0));
      double tot = 0.0;
      int s0 = std::max(0, mm - mp), s1 = std::min(l + mm, l - mp);
      for (int s = s0; s <= s1; s++) {
        double ln = pref - (std::lgamma(l + mm - s + 1.0) + std::lgamma(s + 1.0) +
                            std::lgamma(mp - mm + s + 1.0) + std::lgamma(l - mp - s + 1.0));
        double term = std::exp(ln) * std::pow(cb, (double)(2 * l + mm - mp - 2 * s)) *
                      std::pow(sb, (double)(mp - mm + 2 * s));
        tot += ((mp - mm + s) & 1) ? -term : term;
      }
      d[i * L + j] = tot;
    }
  }
}

static void build_tables(Tables& T) {
  double dbuf[31 * 31];
  // quadrature weights (B_IN=32 -> 64 beta samples)
  double w[64];
  for (int j = 0; j < 64; j++) {
    double s = 0.0;
    for (int k = 0; k < 32; k++)
      s += std::sin((2.0 * j + 1.0) * (2.0 * k + 1.0) * M_PI / 128.0) / (2.0 * k + 1.0);
    w[j] = (2.0 / 32.0) * std::sin(M_PI * (2.0 * j + 1.0) / 128.0) * s * (2.0 * M_PI / 4096.0);
  }
  // Wt[lm][b]
  for (int j = 0; j < 64; j++) {
    double beta = M_PI * (2.0 * j + 1.0) / 128.0;
    for (int l = 0; l < 16; l++) {
      int L = 2 * l + 1;
      h_wigner(l, beta, dbuf);
      for (int i = 0; i < L; i++)
        T.Wt[(l * l + i) * 64 + j] = (float)(w[j] * dbuf[i * L + l]); // column mm=0
    }
  }
  // Y_GRID [g][lm], g = bi*8 + ai, beta=(bi+1)pi/24, alpha=ai*pi/4
  for (int bi = 0; bi < 3; bi++) {
    double beta = (bi + 1) * M_PI / 24.0;
    for (int l = 0; l < 16; l++) {
      int L = 2 * l + 1;
      h_wigner(l, beta, dbuf);
      double coef = std::sqrt((2.0 * l + 1.0) / (4.0 * M_PI));
      for (int ai = 0; ai < 8; ai++) {
        double alpha = ai * M_PI / 4.0;
        int g = bi * 8 + ai;
        for (int i = 0; i < L; i++) {
          int m = i - l;
          double v = coef * dbuf[i * L + l];
          T.Yre[g * NLM + l * l + i] = (float)(v * std::cos(m * alpha));
          T.Yim[g * NLM + l * l + i] = (float)(v * std::sin(m * alpha));
        }
      }
    }
  }
  // mn_off
  {
    int acc = 0;
    for (int t = 0; t < NMN; t++) {
      int m = t / 31 - 15, n = t % 31 - 15;
      int lmin = std::max(std::abs(m), std::abs(n));
      T.mn_off[t] = acc;
      acc += 16 - lmin;
    }
  }
  // Dp[b][packed]
  for (int b = 0; b < 32; b++) {
    double beta = M_PI * (2.0 * b + 1.0) / 64.0;
    for (int l = 0; l < 16; l++) {
      int L = 2 * l + 1;
      h_wigner(l, beta, dbuf);
      for (int i = 0; i < L; i++)
        for (int j = 0; j < L; j++) {
          int m = i - l, n = j - l;
          int t = (m + 15) * 31 + (n + 15);
          int lmin = std::max(std::abs(m), std::abs(n));
          T.Dp[b * NPACK + T.mn_off[t] + (l - lmin)] = (float)((2.0 * l + 1.0) * dbuf[i * L + j]);
        }
    }
  }
  for (int t = 0; t < 64; t++) {
    T.c64[t] = (float)std::cos(2.0 * M_PI * t / 64.0);
    T.s64[t] = (float)std::sin(2.0 * M_PI * t / 64.0);
  }
  for (int t = 0; t < 32; t++) {
    T.c32[t] = (float)std::cos(2.0 * M_PI * t / 32.0);
    T.s32[t] = (float)std::sin(2.0 * M_PI * t / 32.0);
  }
}

// ---------------- kernels ----------------

// K1: fused alpha-DFT (31 bins) + beta contraction.  One block per (z,f).
// x: [32 z][64 f][64 b][64 a] f32 ;  z_arr: [256 lm][32 z][64 f] c64
__global__ __launch_bounds__(256) void k_zbuild(const float* __restrict__ x,
                                                const float* __restrict__ Wt,
                                                const float* __restrict__ tc,
                                                const float* __restrict__ ts,
                                                float2* __restrict__ z_arr) {
  __shared__ float xr[4096];
  __shared__ float fre[1984], fim[1984]; // [b64][m31]
  __shared__ float c64[64], s64[64];
  int zf = blockIdx.x;
  int tid = threadIdx.x;
  if (tid < 64) { c64[tid] = tc[tid]; s64[tid] = ts[tid]; }
  const float* xp = x + (size_t)zf * 4096;
  for (int i = tid; i < 4096; i += 256) xr[i] = xp[i];
  __syncthreads();
  // forward DFT: xf[b][m] = sum_a x[b][a] e^{-2pi i m a/64}, m = mi-15
  for (int idx = tid; idx < 1984; idx += 256) {
    int b = idx / 31, mi = idx - b * 31;
    int m = mi - 15;
    float re = 0.f, im = 0.f;
    const float* row = &xr[b * 64];
    for (int a = 0; a < 64; a++) {
      int t = (m * a) & 63;
      float v = row[a];
      re += v * c64[t];
      im -= v * s64[t];
    }
    fre[idx] = re; fim[idx] = im;
  }
  __syncthreads();
  // z[lm] = sum_b Wt[lm][b] * xf[b][m(lm)]
  {
    int t = tid;
    int l = (int)sqrtf((float)t + 0.5f);
    if (l * l > t) l--;
    else if ((l + 1) * (l + 1) <= t) l++;
    int mi = (t - l * l) - l + 15;
    float zr = 0.f, zi = 0.f;
    const float* wrow = &Wt[t * 64];
    for (int b = 0; b < 64; b++) {
      float wv = wrow[b];
      zr += wv * fre[b * 31 + mi];
      zi += wv * fim[b * 31 + mi];
    }
    z_arr[(size_t)t * 2048 + zf] = make_float2(zr, zi);
  }
}

// K2: y[lm][f][o] = sum_g (kernel[f][o][g]*S) * Y[g][lm].  One block per lm.
__global__ __launch_bounds__(256) void k_ybuild(const float* __restrict__ kern,
                                                const float* __restrict__ Yre,
                                                const float* __restrict__ Yim,
                                                float S, float2* __restrict__ y_arr) {
  __shared__ float yr[24], yi[24];
  int lm = blockIdx.x, tid = threadIdx.x;
  if (tid < 24) { yr[tid] = Yre[tid * NLM + lm]; yi[tid] = Yim[tid * NLM + lm]; }
  __syncthreads();
  for (int p = tid; p < 2048; p += 256) {
    const float* kp = kern + (size_t)p * 24;
    float re = 0.f, im = 0.f;
    for (int g = 0; g < 24; g++) {
      float kv = kp[g] * S;
      re += kv * yr[g];
      im += kv * yi[g];
    }
    y_arr[(size_t)lm * 2048 + p] = make_float2(re, im);
  }
}

// K3: per (l,m1,m2): num = sum_f z1*y2 (c64), den = Re sum_f conj(y1)*y2 (f64 acc),
//     Fz = num/den. One block per pack. Writes Fz [pack][z32][o32] c64.
__global__ __launch_bounds__(256) void k_fz(const float2* __restrict__ z_arr,
                                            const float2* __restrict__ y_arr,
                                            float2* __restrict__ fz) {
  __shared__ float z1r[2048], z1i[2048];  // [z][f]
  __shared__ float y1r[2048], y1i[2048];  // [f][o]
  __shared__ float y2r[2048], y2i[2048];  // [f][o]
  int pack = blockIdx.x, tid = threadIdx.x;
  int l = 15;
  while (d_off[l] > pack) l--;
  int rr = pack - d_off[l];
  int L = 2 * l + 1;
  int i1 = rr / L, i2 = rr - i1 * L;
  int lm1 = l * l + i1, lm2 = l * l + i2;
  for (int i = tid; i < 2048; i += 256) {
    float2 a = z_arr[(size_t)lm1 * 2048 + i]; z1r[i] = a.x; z1i[i] = a.y;
    float2 b = y_arr[(size_t)lm1 * 2048 + i]; y1r[i] = b.x; y1i[i] = b.y;
    float2 c = y_arr[(size_t)lm2 * 2048 + i]; y2r[i] = c.x; y2i[i] = c.y;
  }
  __syncthreads();
  for (int it = 0; it < 4; it++) {
    int idx = tid + it * 256;
    int zz = idx >> 5, oo = idx & 31;
    double den = 0.0;
    float nr = 0.f, ni = 0.f;
    for (int f = 0; f < 64; f++) {
      float ar = z1r[zz * 64 + f], ai = z1i[zz * 64 + f];
      float br = y2r[f * 32 + oo], bi = y2i[f * 32 + oo];
      nr += ar * br - ai * bi;
      ni += ar * bi + ai * br;
      float cr = y1r[f * 32 + zz], ci = y1i[f * 32 + zz];
      den += (double)cr * (double)br + (double)ci * (double)bi;
    }
    float dv = (float)den;
    fz[(size_t)pack * 1024 + idx] = make_float2(nr / dv, ni / dv);
  }
}

// K4: transpose Fz [5456][1024] -> XT [1024][5456] (both c64), tiled.
__global__ __launch_bounds__(256) void k_tr(const float2* __restrict__ fz,
                                            float2* __restrict__ xt) {
  __shared__ float2 tile[32][33];
  int zo0 = blockIdx.x * 32;  // 0..1023
  int p0 = blockIdx.y * 32;   // 0..5455
  int tid = threadIdx.x;
  int c = tid & 31, r0 = tid >> 5;
  for (int r = r0; r < 32; r += 8) {
    int p = p0 + r;
    if (p < NPACK) tile[r][c] = fz[(size_t)p * 1024 + zo0 + c];
  }
  __syncthreads();
  for (int r = r0; r < 32; r += 8) {
    int p = p0 + c;
    if (p < NPACK) xt[(size_t)(zo0 + r) * NPACK + p] = tile[c][r];
  }
}

// K5: synthesis. One block per (z,o). For each b: F[m,n]=sum_l X*D; then 2-stage
// 31x31 -> 32x32 inverse Fourier; out = Re + bias.
__global__ __launch_bounds__(256) void k_synth(const float2* __restrict__ xt,
                                               const float* __restrict__ Dp,
                                               const int* __restrict__ mn_off,
                                               const float* __restrict__ tc32,
                                               const float* __restrict__ ts32,
                                               const float* __restrict__ bias,
                                               float* __restrict__ out) {
  __shared__ float Xr[NPACK], Xi[NPACK];
  __shared__ float Fr[NMN], Fi[NMN];
  __shared__ float Gr[992], Gi[992]; // [m31][k32]
  __shared__ float c32[32], s32[32];
  __shared__ int moff[NMN];
  int zo = blockIdx.x, tid = threadIdx.x;
  if (tid < 32) { c32[tid] = tc32[tid]; s32[tid] = ts32[tid]; }
  for (int i = tid; i < NPACK; i += 256) {
    float2 v = xt[(size_t)zo * NPACK + i];
    Xr[i] = v.x; Xi[i] = v.y;
  }
  for (int i = tid; i < NMN; i += 256) moff[i] = mn_off[i];
  float bv = bias[zo & 31];
  __syncthreads();
  for (int b = 0; b < 32; b++) {
    const float* Db = Dp + b * NPACK;
    // F build
    for (int t = tid; t < NMN; t += 256) {
      int mi = t / 31, ni = t - mi * 31;
      int m = mi - 15, n = ni - 15;
      int am = m < 0 ? -m : m, an = n < 0 ? -n : n;
      int lmin = am > an ? am : an;
      float fr = 0.f, fi2 = 0.f;
      const float* dptr = &Db[moff[t]];
      for (int l = lmin; l < 16; l++) {
        int xi = (l * (4 * l * l - 1)) / 3 + (m + l) * (2 * l + 1) + (n + l);
        float dv = dptr[l - lmin];
        fr += Xr[xi] * dv;
        fi2 += Xi[xi] * dv;
      }
      Fr[t] = fr; Fi[t] = fi2;
    }
    __syncthreads();
    // stage 1 over n: G[m][k] = sum_n F[m,n] e^{+2pi i k n/32}
    for (int t = tid; t < 992; t += 256) {
      int mi = t >> 5, k = t & 31;
      float gr = 0.f, gi = 0.f;
      const float* frow = &Fr[mi * 31];
      const float* firow = &Fi[mi * 31];
      for (int ni = 0; ni < 31; ni++) {
        int tt = (k * (ni - 15)) & 31;
        float cc = c32[tt], ss = s32[tt];
        float a = frow[ni], bb = firow[ni];
        gr += a * cc - bb * ss;
        gi += a * ss + bb * cc;
      }
      Gr[t] = gr; Gi[t] = gi;
    }
    __syncthreads();
    // stage 2 over m: out[j][k] = Re sum_m G[m,k] e^{+2pi i j m/32}
    {
      size_t base = (size_t)zo * 32768 + (size_t)b * 1024;
      for (int t = tid; t < 1024; t += 256) {
        int j = t >> 5, k = t & 31;
        float acc = 0.f;
        for (int mi = 0; mi < 31; mi++) {
          int tt = (j * (mi - 15)) & 31;
          acc += Gr[mi * 32 + k] * c32[tt] - Gi[mi * 32 + k] * s32[tt];
        }
        out[base + t] = acc + bv;
      }
    }
    __syncthreads();
  }
}

// ---------------- launch ----------------
static Tables* g_htbl = nullptr;
static std::once_flag g_once;

static constexpr size_t align256(size_t v) { return (v + 255) & ~(size_t)255; }
static constexpr size_t WS_TBL = 0;
static constexpr size_t WS_Z   = align256(sizeof(Tables));
static constexpr size_t WS_Y   = WS_Z + (size_t)NLM * 2048 * 8;
static constexpr size_t WS_FZ  = WS_Y + (size_t)NLM * 2048 * 8;
static constexpr size_t WS_XT  = WS_FZ + (size_t)NPACK * 1024 * 8;

extern "C" void kernel_launch(void* const* d_in, const int* in_sizes, int n_in,
                              void* d_out, int out_size, void* d_ws, size_t ws_size,
                              hipStream_t stream) {
  std::call_once(g_once, [] {
    hipHostMalloc((void**)&g_htbl, sizeof(Tables));
    build_tables(*g_htbl);
  });

  const float* x = (const float*)d_in[0];
  const float* kern = (const float*)d_in[1];
  const float* bias = (const float*)d_in[2];
  float* out = (float*)d_out;
  char* ws = (char*)d_ws;

  hipMemcpyAsync(ws + WS_TBL, g_htbl, sizeof(Tables), hipMemcpyHostToDevice, stream);

  Tables* dT = (Tables*)(ws + WS_TBL);
  float2* z_arr = (float2*)(ws + WS_Z);
  float2* y_arr = (float2*)(ws + WS_Y);
  float2* fzb   = (float2*)(ws + WS_FZ);
  float2* xtb   = (float2*)(ws + WS_XT);

  float S = (float)(1.0 / std::sqrt(24.0 * 64.0 * 65536.0 / 1024.0));

  k_zbuild<<<2048, 256, 0, stream>>>(x, dT->Wt, dT->c64, dT->s64, z_arr);
  k_ybuild<<<256, 256, 0, stream>>>(kern, dT->Yre, dT->Yim, S, y_arr);
  k_fz<<<NPACK, 256, 0, stream>>>(z_arr, y_arr, fzb);
  k_tr<<<dim3(32, 171), 256, 0, stream>>>(fzb, xtb);
  k_synth<<<1024, 256, 0, stream>>>(xtb, dT->Dp, dT->mn_off, dT->c32, dT->s32, bias, out);
}